// Round 5
// baseline (116.608 us; speedup 1.0000x reference)
//
#include <hip/hip_runtime.h>
#include <hip/hip_fp16.h>
#include <math.h>

// SSIM loss, fused single-pass.
// Stage AB: h-blur of {x, y, x^2+y^2, xy} read directly from global -> LDS fp16,
//           interleaved plane layout, 8 output cols per item.
// Stage C : v-blur in packed fp16 (v_pk_fma_f16) + SSIM map + reduction.
// Input: image, target fp32 [16,3,512,512]. Output: 1 scalar fp32.

#define HH 512
#define WW 512
#define NPLANES 48
#define TW 64                 // output tile width
#define TH 32                 // output tile height
#define RAD 5
#define IH (TH + 2*RAD)       // 42 staged rows
#define KW 11

typedef __attribute__((ext_vector_type(4))) _Float16 h4;
struct alignas(16) h4x2 { h4 a, b; };

struct GaussW { float g[KW]; };

__global__ void ssim_init_out(float* out) { out[0] = 1.0f; }

__global__ __launch_bounds__(256, 7)
void ssim_fused(const float* __restrict__ img, const float* __restrict__ tgt,
                float* __restrict__ out, GaussW gw) {
    // Interleaved h-blurred planes (fp16): [row][col-group(17; 16 used)][2]
    // hb01: [..][0] = blur(x), [..][1] = blur(y)
    // hb23: [..][0] = blur(x^2+y^2), [..][1] = blur(xy)
    __shared__ alignas(16) h4 hb01[IH][17][2];
    __shared__ alignas(16) h4 hb23[IH][17][2];

    const int tid  = threadIdx.x;
    const int p    = blockIdx.z;
    const int r0   = blockIdx.y * TH - RAD;
    const int cb   = blockIdx.x * TW - 8;          // leftmost loaded col (mult of 4)
    const float* ip = img + (size_t)p * (HH * WW);
    const float* tp = tgt + (size_t)p * (HH * WW);

    // ---- Stage AB: global -> h-blur(fp32) -> hb (LDS fp16). 8 cols/item ----
    for (int i = tid; i < IH * 8; i += 256) {
        int r  = i >> 3;
        int ci = i & 7;
        int gr = r0 + r;
        bool rok = (gr >= 0) && (gr < HH);
        const float* xrow = ip + (size_t)gr * WW;
        const float* yrow = tp + (size_t)gr * WW;
        float fx[24], fy[24];
        #pragma unroll
        for (int t = 0; t < 6; ++t) {
            int gc = cb + 8 * ci + 4 * t;
            float4 a = make_float4(0.f, 0.f, 0.f, 0.f), b = a;
            if (rok && gc >= 0 && gc <= WW - 4) {
                a = *(const float4*)(xrow + gc);
                b = *(const float4*)(yrow + gc);
            }
            fx[4*t+0] = a.x; fx[4*t+1] = a.y; fx[4*t+2] = a.z; fx[4*t+3] = a.w;
            fy[4*t+0] = b.x; fy[4*t+1] = b.y; fy[4*t+2] = b.z; fy[4*t+3] = b.w;
        }
        float ss[18], xy[18];
        #pragma unroll
        for (int t = 0; t < 18; ++t) {
            float xv = fx[t + 3], yv = fy[t + 3];
            ss[t] = fmaf(xv, xv, yv * yv);   // x^2 + y^2
            xy[t] = xv * yv;
        }
        float a0[8], a1[8], a2[8], a3[8];
        #pragma unroll
        for (int j = 0; j < 8; ++j) { a0[j]=0.f; a1[j]=0.f; a2[j]=0.f; a3[j]=0.f; }
        #pragma unroll
        for (int k = 0; k < KW; ++k) {
            float g = gw.g[k];
            #pragma unroll
            for (int j = 0; j < 8; ++j) {
                a0[j] = fmaf(g, fx[3 + j + k], a0[j]);
                a1[j] = fmaf(g, fy[3 + j + k], a1[j]);
                a2[j] = fmaf(g, ss[j + k],    a2[j]);
                a3[j] = fmaf(g, xy[j + k],    a3[j]);
            }
        }
        h4x2 w;
        w.a = h4{(_Float16)a0[0], (_Float16)a0[1], (_Float16)a0[2], (_Float16)a0[3]};
        w.b = h4{(_Float16)a1[0], (_Float16)a1[1], (_Float16)a1[2], (_Float16)a1[3]};
        *(h4x2*)&hb01[r][2*ci][0] = w;
        w.a = h4{(_Float16)a0[4], (_Float16)a0[5], (_Float16)a0[6], (_Float16)a0[7]};
        w.b = h4{(_Float16)a1[4], (_Float16)a1[5], (_Float16)a1[6], (_Float16)a1[7]};
        *(h4x2*)&hb01[r][2*ci+1][0] = w;
        w.a = h4{(_Float16)a2[0], (_Float16)a2[1], (_Float16)a2[2], (_Float16)a2[3]};
        w.b = h4{(_Float16)a3[0], (_Float16)a3[1], (_Float16)a3[2], (_Float16)a3[3]};
        *(h4x2*)&hb23[r][2*ci][0] = w;
        w.a = h4{(_Float16)a2[4], (_Float16)a2[5], (_Float16)a2[6], (_Float16)a2[7]};
        w.b = h4{(_Float16)a3[4], (_Float16)a3[5], (_Float16)a3[6], (_Float16)a3[7]};
        *(h4x2*)&hb23[r][2*ci+1][0] = w;
    }
    __syncthreads();

    // ---- Stage C: packed-fp16 v-blur + SSIM; 2 rows x 4 cols per thread ----
    const float C1 = 1e-4f;   // 0.01^2
    const float C2 = 9e-4f;   // 0.03^2
    const int cg = tid & 15;
    const int rg = tid >> 4;                 // output rows 2rg, 2rg+1
    h4 accx[2] = {h4{0,0,0,0}, h4{0,0,0,0}};
    h4 accy[2] = {h4{0,0,0,0}, h4{0,0,0,0}};
    h4 accs[2] = {h4{0,0,0,0}, h4{0,0,0,0}};
    h4 accp[2] = {h4{0,0,0,0}, h4{0,0,0,0}};

    #pragma unroll
    for (int kr = 0; kr < 12; ++kr) {
        int row = rg * 2 + kr;
        h4x2 v01 = *(const h4x2*)&hb01[row][cg][0];
        h4x2 v23 = *(const h4x2*)&hb23[row][cg][0];
        #pragma unroll
        for (int ro = 0; ro < 2; ++ro) {
            int k = kr - ro;
            if (k >= 0 && k < KW) {
                _Float16 gh = (_Float16)gw.g[k];
                h4 gs = h4{gh, gh, gh, gh};
                accx[ro] += gs * v01.a;
                accy[ro] += gs * v01.b;
                accs[ro] += gs * v23.a;
                accp[ro] += gs * v23.b;
            }
        }
    }
    float lsum = 0.f;
    #pragma unroll
    for (int ro = 0; ro < 2; ++ro) {
        #pragma unroll
        for (int co = 0; co < 4; ++co) {
            float mu1 = (float)accx[ro][co], mu2 = (float)accy[ro][co];
            float bss = (float)accs[ro][co], bxy = (float)accp[ro][co];
            float mu1s = mu1 * mu1, mu2s = mu2 * mu2, mu12 = mu1 * mu2;
            float ssum = bss - mu1s - mu2s;   // s1 + s2
            float s12  = bxy - mu12;
            float num = (2.f * mu12 + C1) * (2.f * s12 + C2);
            float den = (mu1s + mu2s + C1) * (ssum + C2);
            lsum = fmaf(num, __builtin_amdgcn_rcpf(den), lsum);
        }
    }

    // ---- block reduction, one atomic per block ----
    for (int off = 32; off > 0; off >>= 1)
        lsum += __shfl_down(lsum, off, 64);
    __shared__ float wsum[4];
    const int wid  = tid >> 6;
    const int lane = tid & 63;
    if (lane == 0) wsum[wid] = lsum;
    __syncthreads();
    if (tid == 0) {
        float bsum = wsum[0] + wsum[1] + wsum[2] + wsum[3];
        const float invN = 1.0f / (float)((size_t)NPLANES * HH * WW);
        atomicAdd(out, -bsum * invN);
    }
}

extern "C" void kernel_launch(void* const* d_in, const int* in_sizes, int n_in,
                              void* d_out, int out_size, void* d_ws, size_t ws_size,
                              hipStream_t stream) {
    const float* img = (const float*)d_in[0];
    const float* tgt = (const float*)d_in[1];
    float* out = (float*)d_out;

    GaussW gw;
    double g[KW], s = 0.0;
    for (int i = 0; i < KW; ++i) {
        double d = (double)(i - KW / 2);
        g[i] = exp(-(d * d) / (2.0 * 1.5 * 1.5));
        s += g[i];
    }
    for (int i = 0; i < KW; ++i) gw.g[i] = (float)(g[i] / s);

    ssim_init_out<<<1, 1, 0, stream>>>(out);

    dim3 grid(WW / TW, HH / TH, NPLANES);  // 8 x 16 x 48
    ssim_fused<<<grid, 256, 0, stream>>>(img, tgt, out, gw);
}

// Round 7
// 66.324 us; speedup vs baseline: 1.7582x; 1.7582x over previous
//
#include <hip/hip_runtime.h>
#include <hip/hip_fp16.h>
#include <math.h>

// SSIM loss via MFMA: both separable blurs are banded-matrix GEMMs on the
// matrix pipe (f16 in, f32 accum). Per 64x32 tile:
//   phase1: load x,y; compute {x,y,x2+y2,xy}; stage as f16 RAW[48][104] LDS
//   phase2: H-blur: OUTH = RAW(48x96) * Wh(96x64), wave q = plane q
//   phase3: V-blur: OUT  = Wv(32x64) * OUTH(64x64), wave w = 16-col slice
//   SSIM map + reduction in registers. 8 tiles per block.
// Wh[d][c] = g[d-c-3] (0<=d-c-3<=10), Wv[i][r] = g[r-i] (0<=r-i<=10),
// g[i] = A * 2^(-B*(i-5)^2) regenerated per-lane; zero-pad via zero weights.
// LDS pad regions (RAW rows 42-47 / cols 80-95, OUTH rows 48-71) are zeroed
// ONCE up front: they carry zero weights, but garbage f16 Inf/NaN x 0 = NaN
// inside MFMA (round-6 failure), so they must be actual zeros.

#define HH 512
#define WW 512
#define NPLANES 48
#define G_TILES 8
#define NBLOCKS 768            // 6144 tiles / 8

typedef _Float16 f16x8 __attribute__((ext_vector_type(8)));
typedef _Float16 f16x4 __attribute__((ext_vector_type(4)));
typedef float f32x4 __attribute__((ext_vector_type(4)));

#define RAW_STRIDE 208         // bytes per RAW row (104 f16); 52 words %32=20 -> 2-way
#define RAW_PLANE  9984        // 48*208
#define OUTH_CSTR  144         // bytes per OUTH col (72 f16); 36 words %32=4 -> 2-way
#define OUTH_PLANE 9216        // 64*144
#define LDS_RAW    39936       // 4*RAW_PLANE
#define LDS_TOTAL  76800       // + 4*OUTH_PLANE

struct WParam { float A, B; };

__global__ void ssim_init_out(float* out) { out[0] = 1.0f; }

__global__ __launch_bounds__(256, 2)
void ssim_mfma(const float* __restrict__ img, const float* __restrict__ tgt,
               float* __restrict__ out, WParam wp) {
    __shared__ alignas(16) char lds[LDS_TOTAL];
    __shared__ float wsum[4];

    const int tid  = threadIdx.x;
    const int wid  = tid >> 6;
    const int lane = tid & 63;
    const int cl   = lane & 15;
    const int am   = lane >> 4;

    // ---- one-time LDS zero-init (pad regions must be true zeros) ----
    for (int i = tid; i < LDS_TOTAL / 4; i += 256)
        ((float*)lds)[i] = 0.f;

    // ---- one-time per-lane weight fragments ----
    f16x8 Bh[4][3];                       // H-blur B operand [nt][kt]
    #pragma unroll
    for (int nt = 0; nt < 4; ++nt) {
        #pragma unroll
        for (int kt = 0; kt < 3; ++kt) {
            f16x8 f;
            #pragma unroll
            for (int j = 0; j < 8; ++j) {
                int d   = 32*kt + 8*am + j;
                int idx = d - (16*nt + cl) - 3;
                float t = (float)(idx - 5);
                float v = wp.A * exp2f(-wp.B * t * t);
                f[j] = ((unsigned)idx <= 10u) ? (_Float16)v : (_Float16)0.f;
            }
            Bh[nt][kt] = f;
        }
    }
    f16x8 Av[2][2];                       // V-blur A operand [mt][kt]
    #pragma unroll
    for (int mt = 0; mt < 2; ++mt) {
        #pragma unroll
        for (int kt = 0; kt < 2; ++kt) {
            f16x8 f;
            #pragma unroll
            for (int j = 0; j < 8; ++j) {
                int r   = 32*kt + 8*am + j;
                int idx = r - (16*mt + cl);
                float t = (float)(idx - 5);
                float v = wp.A * exp2f(-wp.B * t * t);
                f[j] = ((unsigned)idx <= 10u) ? (_Float16)v : (_Float16)0.f;
            }
            Av[mt][kt] = f;
        }
    }
    __syncthreads();

    const float C1 = 1e-4f, C2 = 9e-4f;
    float btot = 0.f;

    for (int g = 0; g < G_TILES; ++g) {
        const int tlin = blockIdx.x * G_TILES + g;
        const int p    = tlin >> 7;            // 128 tiles per plane
        const int rem  = tlin & 127;
        const int R0   = (rem >> 3) * 32;
        const int C0   = (rem & 7) * 64;
        const float* ip = img + (size_t)p * (HH * WW);
        const float* tp = tgt + (size_t)p * (HH * WW);

        // ---- phase 1: stage RAW planes {x, y, x2+y2, xy} as f16 ----
        for (int it = tid; it < 420; it += 256) {
            int r   = it / 10;
            int grp = it - r * 10;
            int gr  = R0 - 5 + r;
            int gc0 = C0 - 8 + grp * 8;
            float4 xa = make_float4(0.f,0.f,0.f,0.f), xb = xa, ya = xa, yb = xa;
            if ((unsigned)gr < (unsigned)HH) {
                const float* xr = ip + (size_t)gr * WW;
                const float* yr = tp + (size_t)gr * WW;
                if ((unsigned)gc0 <= (unsigned)(WW - 4)) {
                    xa = *(const float4*)(xr + gc0);
                    ya = *(const float4*)(yr + gc0);
                }
                if ((unsigned)(gc0 + 4) <= (unsigned)(WW - 4)) {
                    xb = *(const float4*)(xr + gc0 + 4);
                    yb = *(const float4*)(yr + gc0 + 4);
                }
            }
            float fx[8] = {xa.x,xa.y,xa.z,xa.w, xb.x,xb.y,xb.z,xb.w};
            float fy[8] = {ya.x,ya.y,ya.z,ya.w, yb.x,yb.y,yb.z,yb.w};
            f16x8 hx, hy, hs, hp;
            #pragma unroll
            for (int j = 0; j < 8; ++j) {
                hx[j] = (_Float16)fx[j];
                hy[j] = (_Float16)fy[j];
                hs[j] = (_Float16)fmaf(fx[j], fx[j], fy[j]*fy[j]);
                hp[j] = (_Float16)(fx[j] * fy[j]);
            }
            char* base = lds + r * RAW_STRIDE + grp * 16;
            *(f16x8*)(base + 0*RAW_PLANE) = hx;
            *(f16x8*)(base + 1*RAW_PLANE) = hy;
            *(f16x8*)(base + 2*RAW_PLANE) = hs;
            *(f16x8*)(base + 3*RAW_PLANE) = hp;
        }
        __syncthreads();

        // ---- phase 2: H-blur (wave wid handles plane wid) ----
        {
            const char* rawq = lds + wid * RAW_PLANE;
            const int aoff = cl * RAW_STRIDE + am * 16;
            f16x8 Af[3][3];
            #pragma unroll
            for (int mt = 0; mt < 3; ++mt)
                #pragma unroll
                for (int kt = 0; kt < 3; ++kt)
                    Af[mt][kt] = *(const f16x8*)(rawq + aoff + mt*3328 + kt*64);

            char* outq = lds + LDS_RAW + wid * OUTH_PLANE;
            const int woff = cl * OUTH_CSTR + am * 8;
            #pragma unroll
            for (int nt = 0; nt < 4; ++nt) {
                #pragma unroll
                for (int mt = 0; mt < 3; ++mt) {
                    f32x4 acc = {0.f, 0.f, 0.f, 0.f};
                    #pragma unroll
                    for (int kt = 0; kt < 3; ++kt)
                        acc = __builtin_amdgcn_mfma_f32_16x16x32_f16(
                                  Af[mt][kt], Bh[nt][kt], acc, 0, 0, 0);
                    f16x4 h;
                    #pragma unroll
                    for (int j = 0; j < 4; ++j) h[j] = (_Float16)acc[j];
                    *(f16x4*)(outq + woff + nt*2304 + mt*32) = h;
                }
            }
        }
        __syncthreads();

        // ---- phase 3: V-blur (wave wid handles cols 16*wid..16*wid+15) ----
        float lsum = 0.f;
        {
            const char* outb = lds + LDS_RAW;
            const int boff = (16*wid + cl) * OUTH_CSTR + am * 16;
            f32x4 accv[4][2];
            #pragma unroll
            for (int q = 0; q < 4; ++q) {
                f16x8 Bf0 = *(const f16x8*)(outb + q*OUTH_PLANE + boff);
                f16x8 Bf1 = *(const f16x8*)(outb + q*OUTH_PLANE + boff + 64);
                #pragma unroll
                for (int mt = 0; mt < 2; ++mt) {
                    f32x4 acc = {0.f, 0.f, 0.f, 0.f};
                    acc = __builtin_amdgcn_mfma_f32_16x16x32_f16(Av[mt][0], Bf0, acc, 0, 0, 0);
                    acc = __builtin_amdgcn_mfma_f32_16x16x32_f16(Av[mt][1], Bf1, acc, 0, 0, 0);
                    accv[q][mt] = acc;
                }
            }
            #pragma unroll
            for (int mt = 0; mt < 2; ++mt) {
                #pragma unroll
                for (int j = 0; j < 4; ++j) {
                    float mu1 = accv[0][mt][j], mu2 = accv[1][mt][j];
                    float bss = accv[2][mt][j], bxy = accv[3][mt][j];
                    float mu1s = mu1*mu1, mu2s = mu2*mu2, mu12 = mu1*mu2;
                    float ssum = bss - mu1s - mu2s;
                    float s12  = bxy - mu12;
                    float num = (2.f*mu12 + C1) * (2.f*s12 + C2);
                    float den = (mu1s + mu2s + C1) * (ssum + C2);
                    lsum = fmaf(num, __builtin_amdgcn_rcpf(den), lsum);
                }
            }
        }

        // ---- per-tile reduction ----
        for (int off = 32; off > 0; off >>= 1)
            lsum += __shfl_down(lsum, off, 64);
        if (lane == 0) wsum[wid] = lsum;
        __syncthreads();
        if (tid == 0) btot += wsum[0] + wsum[1] + wsum[2] + wsum[3];
    }

    if (tid == 0) {
        const float invN = 1.0f / (float)((size_t)NPLANES * HH * WW);
        atomicAdd(out, -btot * invN);
    }
}

extern "C" void kernel_launch(void* const* d_in, const int* in_sizes, int n_in,
                              void* d_out, int out_size, void* d_ws, size_t ws_size,
                              hipStream_t stream) {
    const float* img = (const float*)d_in[0];
    const float* tgt = (const float*)d_in[1];
    float* out = (float*)d_out;

    // g[i] = exp(-(i-5)^2/4.5)/s = A * 2^(-B*(i-5)^2), A = 1/s, B = log2(e)/4.5
    double s = 0.0;
    for (int i = 0; i < 11; ++i) {
        double d = (double)(i - 5);
        s += exp(-(d * d) / 4.5);
    }
    WParam wp;
    wp.A = (float)(1.0 / s);
    wp.B = (float)(M_LOG2E / 4.5);

    ssim_init_out<<<1, 1, 0, stream>>>(out);
    ssim_mfma<<<NBLOCKS, 256, 0, stream>>>(img, tgt, out, wp);
}

// Round 8
// 49.616 us; speedup vs baseline: 2.3502x; 1.3368x over previous
//
#include <hip/hip_runtime.h>
#include <hip/hip_fp16.h>
#include <math.h>

// SSIM loss via MFMA: both separable blurs are banded-matrix GEMMs on the
// matrix pipe (f16 in, f32 accum). Per 64x32 tile:
//   phase1 : load x,y; compute {x,y,x2+y2,xy}; stage as f16 RAW[48][104] LDS
//   phase2a: each wave drains its RAW plane into registers Af[3][3]
//   phase2b: H-blur OUTH = RAW(48x96) * Wh(96x64); OUTH is ALIASED over RAW
//            (39 KB total LDS -> 4 blocks/CU capacity, 3 co-resident)
//   phase3 : V-blur OUT = Wv(32x64) * OUTH(64x64); SSIM map -> per-thread lsum
//   single reduction after the 8-tile loop.
// Wh[d][c] = g[d-c-3] (0<=d-c-3<=10), Wv[i][r] = g[r-i] (0<=r-i<=10),
// g[i] = A * 2^(-B*(i-5)^2) regenerated per-lane; zero-pad via zero weights.
// NaN-safety under aliasing: every LDS byte is zero-init or finite-f16
// thereafter; all garbage-capable pad elements meet provably-zero weights
// (cols 80-95: d-c-3>=14; k-rows 42-63: r-16mt-cl>=11), finite*0 = 0.

#define HH 512
#define WW 512
#define NPLANES 48
#define G_TILES 8
#define NBLOCKS 768            // 6144 tiles / 8

typedef _Float16 f16x8 __attribute__((ext_vector_type(8)));
typedef _Float16 f16x4 __attribute__((ext_vector_type(4)));
typedef float f32x4 __attribute__((ext_vector_type(4)));

#define RAW_STRIDE 208         // bytes per RAW row (104 f16); 52 words %32=20 -> 2-way
#define RAW_PLANE  9984        // 48*208
#define OUTH_CSTR  144         // bytes per OUTH col (72 f16); 36 words
#define OUTH_PLANE 9216        // 64*144
#define LDS_TOTAL  39936       // 4*RAW_PLANE; OUTH (4*9216=36864) aliased inside

struct WParam { float A, B; };

__global__ void ssim_init_out(float* out) { out[0] = 1.0f; }

__global__ __launch_bounds__(256, 4)
void ssim_mfma(const float* __restrict__ img, const float* __restrict__ tgt,
               float* __restrict__ out, WParam wp) {
    __shared__ alignas(16) char lds[LDS_TOTAL];
    __shared__ float wsum[4];

    const int tid  = threadIdx.x;
    const int wid  = tid >> 6;
    const int lane = tid & 63;
    const int cl   = lane & 15;
    const int am   = lane >> 4;

    // ---- one-time LDS zero-init (finite-everywhere invariant) ----
    for (int i = tid; i < LDS_TOTAL / 4; i += 256)
        ((float*)lds)[i] = 0.f;

    // ---- one-time per-lane weight fragments ----
    f16x8 Bh[4][3];                       // H-blur B operand [nt][kt]
    #pragma unroll
    for (int nt = 0; nt < 4; ++nt) {
        #pragma unroll
        for (int kt = 0; kt < 3; ++kt) {
            f16x8 f;
            #pragma unroll
            for (int j = 0; j < 8; ++j) {
                int d   = 32*kt + 8*am + j;
                int idx = d - (16*nt + cl) - 3;
                float t = (float)(idx - 5);
                float v = wp.A * exp2f(-wp.B * t * t);
                f[j] = ((unsigned)idx <= 10u) ? (_Float16)v : (_Float16)0.f;
            }
            Bh[nt][kt] = f;
        }
    }
    f16x8 Av[2][2];                       // V-blur A operand [mt][kt]
    #pragma unroll
    for (int mt = 0; mt < 2; ++mt) {
        #pragma unroll
        for (int kt = 0; kt < 2; ++kt) {
            f16x8 f;
            #pragma unroll
            for (int j = 0; j < 8; ++j) {
                int r   = 32*kt + 8*am + j;
                int idx = r - (16*mt + cl);
                float t = (float)(idx - 5);
                float v = wp.A * exp2f(-wp.B * t * t);
                f[j] = ((unsigned)idx <= 10u) ? (_Float16)v : (_Float16)0.f;
            }
            Av[mt][kt] = f;
        }
    }
    __syncthreads();

    const float C1 = 1e-4f, C2 = 9e-4f;
    float lsum = 0.f;

    for (int g = 0; g < G_TILES; ++g) {
        const int tlin = blockIdx.x * G_TILES + g;
        const int p    = tlin >> 7;            // 128 tiles per plane
        const int rem  = tlin & 127;
        const int R0   = (rem >> 3) * 32;
        const int C0   = (rem & 7) * 64;
        const float* ip = img + (size_t)p * (HH * WW);
        const float* tp = tgt + (size_t)p * (HH * WW);

        // ---- phase 1: stage RAW planes {x, y, x2+y2, xy} as f16 ----
        for (int it = tid; it < 420; it += 256) {
            int r   = it / 10;
            int grp = it - r * 10;
            int gr  = R0 - 5 + r;
            int gc0 = C0 - 8 + grp * 8;
            float4 xa = make_float4(0.f,0.f,0.f,0.f), xb = xa, ya = xa, yb = xa;
            if ((unsigned)gr < (unsigned)HH) {
                const float* xr = ip + (size_t)gr * WW;
                const float* yr = tp + (size_t)gr * WW;
                if ((unsigned)gc0 <= (unsigned)(WW - 4)) {
                    xa = *(const float4*)(xr + gc0);
                    ya = *(const float4*)(yr + gc0);
                }
                if ((unsigned)(gc0 + 4) <= (unsigned)(WW - 4)) {
                    xb = *(const float4*)(xr + gc0 + 4);
                    yb = *(const float4*)(yr + gc0 + 4);
                }
            }
            float fx[8] = {xa.x,xa.y,xa.z,xa.w, xb.x,xb.y,xb.z,xb.w};
            float fy[8] = {ya.x,ya.y,ya.z,ya.w, yb.x,yb.y,yb.z,yb.w};
            f16x8 hx, hy, hs, hp;
            #pragma unroll
            for (int j = 0; j < 8; ++j) {
                hx[j] = (_Float16)fx[j];
                hy[j] = (_Float16)fy[j];
                hs[j] = (_Float16)fmaf(fx[j], fx[j], fy[j]*fy[j]);
                hp[j] = (_Float16)(fx[j] * fy[j]);
            }
            char* base = lds + r * RAW_STRIDE + grp * 16;
            *(f16x8*)(base + 0*RAW_PLANE) = hx;
            *(f16x8*)(base + 1*RAW_PLANE) = hy;
            *(f16x8*)(base + 2*RAW_PLANE) = hs;
            *(f16x8*)(base + 3*RAW_PLANE) = hp;
        }
        __syncthreads();

        // ---- phase 2a: drain RAW plane wid into registers ----
        f16x8 Af[3][3];
        {
            const char* rawq = lds + wid * RAW_PLANE;
            const int aoff = cl * RAW_STRIDE + am * 16;
            #pragma unroll
            for (int mt = 0; mt < 3; ++mt)
                #pragma unroll
                for (int kt = 0; kt < 3; ++kt)
                    Af[mt][kt] = *(const f16x8*)(rawq + aoff + mt*3328 + kt*64);
        }
        __syncthreads();   // RAW fully drained before OUTH overwrites it

        // ---- phase 2b: H-blur MFMA, write OUTH (aliased over RAW) ----
        {
            char* outq = lds + wid * OUTH_PLANE;
            const int woff = cl * OUTH_CSTR + am * 8;
            #pragma unroll
            for (int nt = 0; nt < 4; ++nt) {
                #pragma unroll
                for (int mt = 0; mt < 3; ++mt) {
                    f32x4 acc = {0.f, 0.f, 0.f, 0.f};
                    #pragma unroll
                    for (int kt = 0; kt < 3; ++kt)
                        acc = __builtin_amdgcn_mfma_f32_16x16x32_f16(
                                  Af[mt][kt], Bh[nt][kt], acc, 0, 0, 0);
                    f16x4 h;
                    #pragma unroll
                    for (int j = 0; j < 4; ++j) h[j] = (_Float16)acc[j];
                    *(f16x4*)(outq + woff + nt*2304 + mt*32) = h;
                }
            }
        }
        __syncthreads();

        // ---- phase 3: V-blur (wave wid handles cols 16*wid..16*wid+15) ----
        {
            const int boff = (16*wid + cl) * OUTH_CSTR + am * 16;
            f32x4 accv[4][2];
            #pragma unroll
            for (int q = 0; q < 4; ++q) {
                f16x8 Bf0 = *(const f16x8*)(lds + q*OUTH_PLANE + boff);
                f16x8 Bf1 = *(const f16x8*)(lds + q*OUTH_PLANE + boff + 64);
                #pragma unroll
                for (int mt = 0; mt < 2; ++mt) {
                    f32x4 acc = {0.f, 0.f, 0.f, 0.f};
                    acc = __builtin_amdgcn_mfma_f32_16x16x32_f16(Av[mt][0], Bf0, acc, 0, 0, 0);
                    acc = __builtin_amdgcn_mfma_f32_16x16x32_f16(Av[mt][1], Bf1, acc, 0, 0, 0);
                    accv[q][mt] = acc;
                }
            }
            #pragma unroll
            for (int mt = 0; mt < 2; ++mt) {
                #pragma unroll
                for (int j = 0; j < 4; ++j) {
                    float mu1 = accv[0][mt][j], mu2 = accv[1][mt][j];
                    float bss = accv[2][mt][j], bxy = accv[3][mt][j];
                    float mu1s = mu1*mu1, mu2s = mu2*mu2, mu12 = mu1*mu2;
                    float ssum = bss - mu1s - mu2s;
                    float s12  = bxy - mu12;
                    float num = (2.f*mu12 + C1) * (2.f*s12 + C2);
                    float den = (mu1s + mu2s + C1) * (ssum + C2);
                    lsum = fmaf(num, __builtin_amdgcn_rcpf(den), lsum);
                }
            }
        }
        __syncthreads();   // OUTH fully read before next phase-1 overwrites
    }

    // ---- single block reduction + one atomic ----
    for (int off = 32; off > 0; off >>= 1)
        lsum += __shfl_down(lsum, off, 64);
    if (lane == 0) wsum[wid] = lsum;
    __syncthreads();
    if (tid == 0) {
        float bsum = wsum[0] + wsum[1] + wsum[2] + wsum[3];
        const float invN = 1.0f / (float)((size_t)NPLANES * HH * WW);
        atomicAdd(out, -bsum * invN);
    }
}

extern "C" void kernel_launch(void* const* d_in, const int* in_sizes, int n_in,
                              void* d_out, int out_size, void* d_ws, size_t ws_size,
                              hipStream_t stream) {
    const float* img = (const float*)d_in[0];
    const float* tgt = (const float*)d_in[1];
    float* out = (float*)d_out;

    // g[i] = exp(-(i-5)^2/4.5)/s = A * 2^(-B*(i-5)^2), A = 1/s, B = log2(e)/4.5
    double s = 0.0;
    for (int i = 0; i < 11; ++i) {
        double d = (double)(i - 5);
        s += exp(-(d * d) / 4.5);
    }
    WParam wp;
    wp.A = (float)(1.0 / s);
    wp.B = (float)(M_LOG2E / 4.5);

    ssim_init_out<<<1, 1, 0, stream>>>(out);
    ssim_mfma<<<NBLOCKS, 256, 0, stream>>>(img, tgt, out, wp);
}